// Round 1
// baseline (740.737 us; speedup 1.0000x reference)
//
#include <hip/hip_runtime.h>
#include <stdint.h>

// Problem constants (from reference)
#define EN 800000     // edges
#define NN 50000      // nodes
#define HID 256       // hidden
#define ED 64         // edge dim
#define LN_EPS 1e-5f

typedef __attribute__((ext_vector_type(8))) short bf8_t;   // 8 x bf16 (4 VGPRs) MFMA operand
typedef __attribute__((ext_vector_type(4))) float f32x4;   // MFMA accumulator

union BF8 { unsigned short u[8]; bf8_t v; };

__device__ __forceinline__ unsigned short f2bf(float f) {
  union { float f; uint32_t u; } x; x.f = f;
  return (unsigned short)((x.u + 0x7FFFu + ((x.u >> 16) & 1u)) >> 16);  // RNE
}
__device__ __forceinline__ float bf2f(uint32_t h) {
  union { uint32_t u; float f; } x; x.u = h << 16;
  return x.f;
}
__device__ __forceinline__ bf8_t pack8(float4 f0, float4 f1) {
  BF8 u;
  u.u[0] = f2bf(f0.x); u.u[1] = f2bf(f0.y); u.u[2] = f2bf(f0.z); u.u[3] = f2bf(f0.w);
  u.u[4] = f2bf(f1.x); u.u[5] = f2bf(f1.y); u.u[6] = f2bf(f1.z); u.u[7] = f2bf(f1.w);
  return u.v;
}

#define MFMA(a, b, c) __builtin_amdgcn_mfma_f32_16x16x32_bf16((a), (b), (c), 0, 0, 0)

// ---------------------------------------------------------------------------
// K0: fp32 -> bf16 weight conversion into workspace
// ---------------------------------------------------------------------------
__global__ void k_cvt_w(const float* __restrict__ W1, const float* __restrict__ W2,
                        const float* __restrict__ EL,
                        unsigned short* __restrict__ W1b, unsigned short* __restrict__ W2b,
                        unsigned short* __restrict__ ELb) {
  int i = blockIdx.x * blockDim.x + threadIdx.x;
  int stride = blockDim.x * gridDim.x;
  for (int j = i; j < HID * HID; j += stride) W1b[j] = f2bf(W1[j]);
  for (int j = i; j < ED * HID; j += stride) W2b[j] = f2bf(W2[j]);
  for (int j = i; j < HID * ED; j += stride) ELb[j] = f2bf(EL[j]);
}

// ---------------------------------------------------------------------------
// K1: node projections  Psrc = node_attr @ src_lin^T,  Pdst = node_attr @ dst_lin^T + bias
//     output bf16 tables [NN][256].  64-row tile per WG, 4 waves, 16x16x32 MFMA.
// LDS tile swizzle: rows of 512B split in 16B chunks, chunk ^= (row & 7)  [T2]
// ---------------------------------------------------------------------------
__launch_bounds__(256)
__global__ void k_node_proj(const float* __restrict__ node_attr,
                            const float* __restrict__ src_lin,
                            const float* __restrict__ dst_lin,
                            const float* __restrict__ bias,
                            unsigned short* __restrict__ Psrc,
                            unsigned short* __restrict__ Pdst) {
  __shared__ __align__(16) char s_a[64 * 512];  // [64][256] bf16, swizzled
  const int tid = threadIdx.x;
  const int wid = tid >> 6;
  const int lane = tid & 63;
  const int l16 = lane & 15, lq = lane >> 4;
  const int m0 = blockIdx.x * 64;

  // stage node rows fp32 -> bf16 LDS (2 float4 = 8 elems -> one 16B chunk)
  for (int c = tid; c < 64 * 32; c += 256) {
    int row = c >> 5, kc = c & 31;
    int grow = m0 + row;
    bf8_t val;
    if (grow < NN) {
      const float4* p = (const float4*)(node_attr + grow * HID + kc * 8);
      val = pack8(p[0], p[1]);
    } else {
      BF8 z;
      #pragma unroll
      for (int j = 0; j < 8; ++j) z.u[j] = 0;
      val = z.v;
    }
    *(bf8_t*)(s_a + row * 512 + ((kc ^ (row & 7)) << 4)) = val;
  }
  __syncthreads();

  const int n0 = wid * 64;  // each wave owns a 64-wide N slice
  for (int pass = 0; pass < 2; ++pass) {
    const float* W = pass ? dst_lin : src_lin;
    f32x4 acc[4][4] = {};
    #pragma unroll
    for (int ks = 0; ks < 8; ++ks) {
      bf8_t a[4], b[4];
      #pragma unroll
      for (int mi = 0; mi < 4; ++mi) {
        int row = mi * 16 + l16;
        a[mi] = *(const bf8_t*)(s_a + row * 512 + (((ks * 4 + lq) ^ (row & 7)) << 4));
      }
      #pragma unroll
      for (int ni = 0; ni < 4; ++ni) {
        const float4* p = (const float4*)(W + (n0 + ni * 16 + l16) * HID + ks * 32 + lq * 8);
        b[ni] = pack8(p[0], p[1]);
      }
      #pragma unroll
      for (int mi = 0; mi < 4; ++mi)
        #pragma unroll
        for (int ni = 0; ni < 4; ++ni)
          acc[mi][ni] = MFMA(a[mi], b[ni], acc[mi][ni]);
    }
    unsigned short* P = pass ? Pdst : Psrc;
    #pragma unroll
    for (int ni = 0; ni < 4; ++ni) {
      int col = n0 + ni * 16 + l16;
      float bia = pass ? bias[col] : 0.f;
      #pragma unroll
      for (int mi = 0; mi < 4; ++mi) {
        #pragma unroll
        for (int r = 0; r < 4; ++r) {
          int row = m0 + mi * 16 + lq * 4 + r;   // C layout: col=lane&15, row=(lane>>4)*4+r
          if (row < NN) P[row * HID + col] = f2bf(acc[mi][ni][r] + bia);
        }
      }
    }
  }
}

// ---------------------------------------------------------------------------
// K2: fused per-edge pipeline, 64 edges per WG, 4 waves.
//   h  = relu(edge_attr@EL^T + Psrc[src] + Pdst[dst])
//   h1 = relu(h@W1^T + b1)
//   y  = LN(h1@W2^T + b2) * gamma + beta
// s_h [64][256] bf16 reused: gathered sums -> H0 -> H1 (barriers between phases)
// ---------------------------------------------------------------------------
__launch_bounds__(256)
__global__ void k_edge_main(const float* __restrict__ edge_attr,
                            const int* __restrict__ edge_index,
                            const unsigned short* __restrict__ Psrc,
                            const unsigned short* __restrict__ Pdst,
                            const unsigned short* __restrict__ ELb,
                            const unsigned short* __restrict__ W1b,
                            const unsigned short* __restrict__ W2b,
                            const float* __restrict__ b1,
                            const float* __restrict__ b2,
                            const float* __restrict__ gam,
                            const float* __restrict__ bet,
                            float* __restrict__ out) {
  __shared__ __align__(16) char s_h[64 * 512];  // [64][256] bf16, swizzled
  __shared__ __align__(16) char s_e[64 * 128];  // [64][64] bf16, swizzled
  __shared__ int s_src[64], s_dst[64];

  const int tid = threadIdx.x;
  const int wid = tid >> 6;
  const int lane = tid & 63;
  const int l16 = lane & 15, lq = lane >> 4;
  const int e0 = blockIdx.x * 64;

  if (tid < 64) s_src[tid] = edge_index[e0 + tid];
  else if (tid < 128) s_dst[tid - 64] = edge_index[EN + e0 + (tid - 64)];

  // stage edge_attr [64][64] fp32 -> bf16 LDS
  #pragma unroll
  for (int i = 0; i < 2; ++i) {
    int c = tid + i * 256;          // 512 chunks of 16B
    int row = c >> 3, kc = c & 7;
    const float4* p = (const float4*)(edge_attr + (e0 + row) * ED + kc * 8);
    *(bf8_t*)(s_e + row * 128 + ((kc ^ (row & 7)) << 4)) = pack8(p[0], p[1]);
  }
  __syncthreads();

  // gather: HS[row] = Psrc[src] + Pdst[dst] (bf16), one row per wave-iteration
  #pragma unroll 4
  for (int i = 0; i < 16; ++i) {
    int er = wid * 16 + i;
    int s = s_src[er], d = s_dst[er];
    const uint2* ps = (const uint2*)(Psrc + s * HID) + lane;   // 8B/lane, 512B/row
    const uint2* pd = (const uint2*)(Pdst + d * HID) + lane;
    uint2 a = *ps, b = *pd;
    float v0 = bf2f(a.x & 0xffffu) + bf2f(b.x & 0xffffu);
    float v1 = bf2f(a.x >> 16)     + bf2f(b.x >> 16);
    float v2 = bf2f(a.y & 0xffffu) + bf2f(b.y & 0xffffu);
    float v3 = bf2f(a.y >> 16)     + bf2f(b.y >> 16);
    uint2 o;
    o.x = (uint32_t)f2bf(v0) | ((uint32_t)f2bf(v1) << 16);
    o.y = (uint32_t)f2bf(v2) | ((uint32_t)f2bf(v3) << 16);
    int chunk = lane >> 1;
    *(uint2*)(s_h + er * 512 + ((chunk ^ (er & 7)) << 4) + ((lane & 1) << 3)) = o;
  }

  // GEMM1: edge_attr @ EL^T  (K=64, 2 K-steps), wave owns N-slice n0..n0+63
  const int n0 = wid * 64;
  f32x4 acc[4][4] = {};
  #pragma unroll
  for (int ks = 0; ks < 2; ++ks) {
    bf8_t a[4], b[4];
    #pragma unroll
    for (int mi = 0; mi < 4; ++mi) {
      int row = mi * 16 + l16;
      a[mi] = *(const bf8_t*)(s_e + row * 128 + (((ks * 4 + lq) ^ (row & 7)) << 4));
    }
    #pragma unroll
    for (int ni = 0; ni < 4; ++ni)
      b[ni] = *(const bf8_t*)(ELb + (n0 + ni * 16 + l16) * ED + ks * 32 + lq * 8);
    #pragma unroll
    for (int mi = 0; mi < 4; ++mi)
      #pragma unroll
      for (int ni = 0; ni < 4; ++ni)
        acc[mi][ni] = MFMA(a[mi], b[ni], acc[mi][ni]);
  }
  __syncthreads();   // gather writes from all waves now visible

  // epilogue1: H0 = relu(C1 + HS) in place (each lane RMWs unique cells)
  #pragma unroll
  for (int mi = 0; mi < 4; ++mi) {
    #pragma unroll
    for (int ni = 0; ni < 4; ++ni) {
      int col = n0 + ni * 16 + l16;
      #pragma unroll
      for (int r = 0; r < 4; ++r) {
        int row = mi * 16 + lq * 4 + r;
        unsigned short* p = (unsigned short*)(s_h + row * 512 +
                              (((col >> 3) ^ (row & 7)) << 4) + ((col & 7) << 1));
        float v = acc[mi][ni][r] + bf2f(*p);
        *p = f2bf(fmaxf(v, 0.f));
      }
    }
  }
  __syncthreads();

  // GEMM2: H0 @ W1^T  (K=256, 8 K-steps), B streamed from L2
  #pragma unroll
  for (int mi = 0; mi < 4; ++mi)
    #pragma unroll
    for (int ni = 0; ni < 4; ++ni)
      acc[mi][ni] = (f32x4){0.f, 0.f, 0.f, 0.f};
  #pragma unroll
  for (int ks = 0; ks < 8; ++ks) {
    bf8_t a[4], b[4];
    #pragma unroll
    for (int mi = 0; mi < 4; ++mi) {
      int row = mi * 16 + l16;
      a[mi] = *(const bf8_t*)(s_h + row * 512 + (((ks * 4 + lq) ^ (row & 7)) << 4));
    }
    #pragma unroll
    for (int ni = 0; ni < 4; ++ni)
      b[ni] = *(const bf8_t*)(W1b + (n0 + ni * 16 + l16) * HID + ks * 32 + lq * 8);
    #pragma unroll
    for (int mi = 0; mi < 4; ++mi)
      #pragma unroll
      for (int ni = 0; ni < 4; ++ni)
        acc[mi][ni] = MFMA(a[mi], b[ni], acc[mi][ni]);
  }
  __syncthreads();   // everyone done reading H0

  // epilogue2: H1 = relu(C2 + b1) -> s_h
  #pragma unroll
  for (int ni = 0; ni < 4; ++ni) {
    int col = n0 + ni * 16 + l16;
    float bia = b1[col];
    #pragma unroll
    for (int mi = 0; mi < 4; ++mi) {
      #pragma unroll
      for (int r = 0; r < 4; ++r) {
        int row = mi * 16 + lq * 4 + r;
        *(unsigned short*)(s_h + row * 512 +
            (((col >> 3) ^ (row & 7)) << 4) + ((col & 7) << 1))
            = f2bf(fmaxf(acc[mi][ni][r] + bia, 0.f));
      }
    }
  }
  __syncthreads();

  // GEMM3: H1 @ W2^T -> [64][64]; wave owns rows wid*16..+15, full 64 cols
  f32x4 acc3[4] = {};
  #pragma unroll
  for (int ks = 0; ks < 8; ++ks) {
    int row = wid * 16 + l16;
    bf8_t a = *(const bf8_t*)(s_h + row * 512 + (((ks * 4 + lq) ^ (row & 7)) << 4));
    #pragma unroll
    for (int ni = 0; ni < 4; ++ni) {
      bf8_t b = *(const bf8_t*)(W2b + (ni * 16 + l16) * HID + ks * 32 + lq * 8);
      acc3[ni] = MFMA(a, b, acc3[ni]);
    }
  }

  // epilogue3: +b2, LayerNorm over 64 cols, fp32 store
  float vals[4][4];
  float sum[4] = {0.f, 0.f, 0.f, 0.f}, ssq[4] = {0.f, 0.f, 0.f, 0.f};
  #pragma unroll
  for (int ni = 0; ni < 4; ++ni) {
    int col = ni * 16 + l16;
    float bia = b2[col];
    #pragma unroll
    for (int r = 0; r < 4; ++r) {
      float v = acc3[ni][r] + bia;
      vals[ni][r] = v;
      sum[r] += v;
      ssq[r] += v * v;
    }
  }
  // reduce across the 16 lanes holding one row (consecutive lanes lq*16..lq*16+15)
  #pragma unroll
  for (int m = 1; m < 16; m <<= 1) {
    #pragma unroll
    for (int r = 0; r < 4; ++r) {
      sum[r] += __shfl_xor(sum[r], m, 64);
      ssq[r] += __shfl_xor(ssq[r], m, 64);
    }
  }
  float mu[4], rstd[4];
  #pragma unroll
  for (int r = 0; r < 4; ++r) {
    mu[r] = sum[r] * (1.f / 64.f);
    float var = ssq[r] * (1.f / 64.f) - mu[r] * mu[r];
    rstd[r] = rsqrtf(var + LN_EPS);
  }
  #pragma unroll
  for (int ni = 0; ni < 4; ++ni) {
    int col = ni * 16 + l16;
    float g = gam[col], be = bet[col];
    #pragma unroll
    for (int r = 0; r < 4; ++r) {
      int row = e0 + wid * 16 + lq * 4 + r;
      out[row * ED + col] = (vals[ni][r] - mu[r]) * rstd[r] * g + be;
    }
  }
}

// ---------------------------------------------------------------------------
// Workspace layout (bytes, 256-aligned):
//   Psrc bf16 [50000][256] @ 0          (25,600,000)
//   Pdst bf16 [50000][256] @ 25,600,000 (25,600,000)
//   W1b  bf16 [256][256]   @ 51,200,000 (131,072)
//   W2b  bf16 [64][256]    @ 51,331,072 (32,768)
//   ELb  bf16 [256][64]    @ 51,363,840 (32,768)
// total 51,396,608 B
// ---------------------------------------------------------------------------
extern "C" void kernel_launch(void* const* d_in, const int* in_sizes, int n_in,
                              void* d_out, int out_size, void* d_ws, size_t ws_size,
                              hipStream_t stream) {
  const float* edge_attr = (const float*)d_in[0];
  const float* node_attr = (const float*)d_in[1];
  const int* edge_index = (const int*)d_in[2];   // JAX default x64-off -> int32
  const float* edge_lin = (const float*)d_in[3];
  const float* src_lin = (const float*)d_in[4];
  const float* dst_lin = (const float*)d_in[5];
  const float* bias = (const float*)d_in[6];
  const float* W1 = (const float*)d_in[7];
  const float* b1 = (const float*)d_in[8];
  const float* W2 = (const float*)d_in[9];
  const float* b2 = (const float*)d_in[10];
  const float* gam = (const float*)d_in[11];
  const float* bet = (const float*)d_in[12];
  float* out = (float*)d_out;

  char* ws = (char*)d_ws;
  unsigned short* Psrc = (unsigned short*)(ws + 0);
  unsigned short* Pdst = (unsigned short*)(ws + 25600000);
  unsigned short* W1b = (unsigned short*)(ws + 51200000);
  unsigned short* W2b = (unsigned short*)(ws + 51331072);
  unsigned short* ELb = (unsigned short*)(ws + 51363840);

  hipLaunchKernelGGL(k_cvt_w, dim3(128), dim3(256), 0, stream,
                     W1, W2, edge_lin, W1b, W2b, ELb);
  hipLaunchKernelGGL(k_node_proj, dim3((NN + 63) / 64), dim3(256), 0, stream,
                     node_attr, src_lin, dst_lin, bias, Psrc, Pdst);
  hipLaunchKernelGGL(k_edge_main, dim3(EN / 64), dim3(256), 0, stream,
                     edge_attr, edge_index, Psrc, Pdst, ELb, W1b, W2b,
                     b1, b2, gam, bet, out);
}